// Round 1
// 101.465 us; speedup vs baseline: 1.1243x; 1.1243x over previous
//
#include <hip/hip_runtime.h>

#define VOCAB 50257
#define EMBED 256
#define OUT 5
#define BATCH 512
#define SEQ 512
#define PADO 8  // padded stride of embW rows (32 B -> aligned float4+float gathers)

// Kernel 1: embW[v][o] = dot(emb[v,:], W[o,:]).
// Persistent blocks (1024 = 4/CU). W lives in registers: lane holds the
// 16-float chunk (col = lane&15) of every W row -> loaded once per wave.
// Each wave processes 4 vocab rows per iteration: 16 lanes per row, so the
// cross-lane reduction is 4 shuffle steps (width 16) instead of 6 (width 64),
// and no LDS / __syncthreads at all.
__global__ __launch_bounds__(256) void k_embw(const float* __restrict__ emb,
                                              const float* __restrict__ W,
                                              float* __restrict__ embW) {
    const int lane = threadIdx.x & 63;
    const int sub  = lane >> 4;   // which row of the quad this lane works on
    const int col  = lane & 15;   // 16-float chunk within the row

    // Per-lane register copy of W chunk: w[o][c] = W[o][col*16 + c*4 .. +3]
    float4 w[OUT][4];
#pragma unroll
    for (int o = 0; o < OUT; ++o)
#pragma unroll
        for (int c = 0; c < 4; ++c)
            w[o][c] = *(const float4*)(W + o * EMBED + col * 16 + c * 4);

    const int waveId = (int)((blockIdx.x * 256u + threadIdx.x) >> 6);
    const int nWaves = (int)gridDim.x * 4;          // 4096 waves
    const int nQuad  = (VOCAB + 3) / 4;             // 12565 row-quads

    for (int q = waveId; q < nQuad; q += nWaves) {
        const int v = q * 4 + sub;
        float p[OUT] = {0.f, 0.f, 0.f, 0.f, 0.f};
        if (v < VOCAB) {
            const float* row = emb + (size_t)v * EMBED + col * 16;
#pragma unroll
            for (int c = 0; c < 4; ++c) {
                const float4 e = *(const float4*)(row + c * 4);
#pragma unroll
                for (int o = 0; o < OUT; ++o)
                    p[o] += e.x * w[o][c].x + e.y * w[o][c].y +
                            e.z * w[o][c].z + e.w * w[o][c].w;
            }
        }
        // Reduce within each 16-lane group (4 steps x 5 outputs).
#pragma unroll
        for (int o = 0; o < OUT; ++o) {
#pragma unroll
            for (int off = 8; off > 0; off >>= 1)
                p[o] += __shfl_down(p[o], off, 16);
        }
        if (col == 0 && v < VOCAB) {
            float* dst = embW + (size_t)v * PADO;   // 32 B-aligned
            *(float4*)dst = make_float4(p[0], p[1], p[2], p[3]);
            dst[4] = p[4];
        }
    }
}

// Kernel 2: one block per sample. int2 token loads (2 tokens/thread covers
// SEQ=512 exactly); aligned 32 B-stride gathers from padded embW; then
// logits -> log-softmax -> per-sample NLL.
__global__ __launch_bounds__(256) void k_pool(const int* __restrict__ x,
                                              const int* __restrict__ lengths,
                                              const int* __restrict__ y,
                                              const float* __restrict__ bias,
                                              const float* __restrict__ embW,
                                              float* __restrict__ losses) {
    const int b   = blockIdx.x;
    const int len = lengths[b];
    const int tid = threadIdx.x;

    const int2 tk = ((const int2*)(x + (size_t)b * SEQ))[tid];

    float acc[OUT] = {0.f, 0.f, 0.f, 0.f, 0.f};
    if (2 * tid < len) {
        const float* r = embW + (size_t)tk.x * PADO;
        const float4 a = *(const float4*)r;
        const float a4 = r[4];
        acc[0] += a.x; acc[1] += a.y; acc[2] += a.z; acc[3] += a.w; acc[4] += a4;
    }
    if (2 * tid + 1 < len) {
        const float* r = embW + (size_t)tk.y * PADO;
        const float4 a = *(const float4*)r;
        const float a4 = r[4];
        acc[0] += a.x; acc[1] += a.y; acc[2] += a.z; acc[3] += a.w; acc[4] += a4;
    }

#pragma unroll
    for (int o = 0; o < OUT; ++o) {
#pragma unroll
        for (int off = 32; off > 0; off >>= 1)
            acc[o] += __shfl_down(acc[o], off, 64);
    }

    __shared__ float red[4][OUT];
    const int wave = tid >> 6;
    const int lane = tid & 63;
    if (lane == 0) {
#pragma unroll
        for (int o = 0; o < OUT; ++o) red[wave][o] = acc[o];
    }
    __syncthreads();

    if (tid == 0) {
        float logits[OUT];
        const float inv = 1.0f / (float)len;
#pragma unroll
        for (int o = 0; o < OUT; ++o)
            logits[o] = (red[0][o] + red[1][o] + red[2][o] + red[3][o]) * inv + bias[o];

        float m = logits[0];
#pragma unroll
        for (int o = 1; o < OUT; ++o) m = fmaxf(m, logits[o]);
        float sum = 0.f;
#pragma unroll
        for (int o = 0; o < OUT; ++o) sum += __expf(logits[o] - m);
        const float lse = m + __logf(sum);
        losses[b] = lse - logits[y[b]];
    }
}

// Kernel 3: deterministic mean over 512 per-sample losses.
__global__ __launch_bounds__(256) void k_reduce(const float* __restrict__ losses,
                                                float* __restrict__ out) {
    float v = losses[threadIdx.x] + losses[threadIdx.x + 256];
#pragma unroll
    for (int off = 32; off > 0; off >>= 1)
        v += __shfl_down(v, off, 64);
    __shared__ float red[4];
    if ((threadIdx.x & 63) == 0) red[threadIdx.x >> 6] = v;
    __syncthreads();
    if (threadIdx.x == 0)
        out[0] = (red[0] + red[1] + red[2] + red[3]) * (1.0f / (float)BATCH);
}

extern "C" void kernel_launch(void* const* d_in, const int* in_sizes, int n_in,
                              void* d_out, int out_size, void* d_ws, size_t ws_size,
                              hipStream_t stream) {
    const int*   x       = (const int*)d_in[0];
    const int*   lengths = (const int*)d_in[1];
    const int*   y       = (const int*)d_in[2];
    const float* emb     = (const float*)d_in[3];
    const float* W       = (const float*)d_in[4];
    const float* bias    = (const float*)d_in[5];

    float* embW   = (float*)d_ws;                     // VOCAB*PADO floats (~1.6 MB)
    float* losses = embW + (size_t)VOCAB * PADO;      // BATCH floats

    k_embw<<<1024, 256, 0, stream>>>(emb, W, embW);
    k_pool<<<BATCH, 256, 0, stream>>>(x, lengths, y, bias, embW, losses);
    k_reduce<<<1, 256, 0, stream>>>(losses, (float*)d_out);
}